// Round 2
// baseline (243.463 us; speedup 1.0000x reference)
//
#include <hip/hip_runtime.h>

#define N 4096
#define CIN 64
#define NB 2
#define NBLK 512u

typedef unsigned short u16;
typedef short bf16x8 __attribute__((ext_vector_type(8)));
typedef float f32x4 __attribute__((ext_vector_type(4)));

// workspace layout (float offsets). OFF_V region holds bf16 (u16) V.
// OFF_QK holds qkj[n][8] = q[n] . kj
#define OFF_QT 0
#define OFF_KT (OFF_QT + NB*N*8)
#define OFF_JT (OFF_KT + NB*N*8)
#define OFF_V  (OFF_JT + NB*N*8)
#define OFF_QK (OFF_V + NB*CIN*N)
#define OFF_MX (OFF_QK + NB*N*8)
#define OFF_SC (OFF_MX + NB*N)
#define OFF_BAR (OFF_SC + NB*N)     // 2 uint barrier counters (memset to 0 pre-launch)

__device__ __forceinline__ u16 f2bf(float f) {
    union { float f; unsigned u; } v; v.f = f;
    unsigned r = (v.u + 0x7fffu + ((v.u >> 16) & 1u)) >> 16;  // RNE
    return (u16)r;
}

// Hand-rolled grid barrier. Safe because __launch_bounds__(256,2) + 20.5KiB LDS
// guarantees 2 blocks/CU -> all 512 blocks of the grid are co-resident on the
// 256-CU device. RELEASE RMW flushes writer-XCD L2; RELAXED agent-scope atomic
// polls are serviced at the coherent point (no stale-L2 spin); trailing
// __threadfence() is the acquire for the whole block (per-CU L1 is shared).
__device__ __forceinline__ void grid_barrier(unsigned* bar) {
    __syncthreads();
    if (threadIdx.x == 0) {
        __hip_atomic_fetch_add(bar, 1u, __ATOMIC_RELEASE, __HIP_MEMORY_SCOPE_AGENT);
        while (__hip_atomic_load(bar, __ATOMIC_RELAXED, __HIP_MEMORY_SCOPE_AGENT) < NBLK)
            __builtin_amdgcn_s_sleep(2);
        __threadfence();
    }
    __syncthreads();
}

// LDS overlay: phase B (kj reduction) vs phase C (pass2 tiles). Max 20480 B.
struct SmemB { float kjpart[4][64]; float kjs[64]; };
struct SmemC { u16 Pt[64][72]; u16 Vt[64][72]; float ks[64][8]; };
union Smem { SmemB b; SmemC c; };

__global__ __launch_bounds__(256, 2) void fused(
        const float* __restrict__ x,
        const float* __restrict__ wq, const float* __restrict__ bq,
        const float* __restrict__ wk, const float* __restrict__ bk,
        const float* __restrict__ wj, const float* __restrict__ bj,
        const float* __restrict__ wv, const float* __restrict__ bv,
        const float* __restrict__ gamma,
        float* __restrict__ ws, u16* __restrict__ vbf, float* __restrict__ out) {
    __shared__ __align__(16) Smem shm;
    const int t   = threadIdx.x;
    const int blk = blockIdx.x;            // 512 blocks
    unsigned* bar = (unsigned*)(ws + OFF_BAR);

    // ================= phase A: prep (old grid (16,16,2) == 512 blocks) =====
    {
        const int bx = blk & 15;
        const int y  = (blk >> 4) & 15;
        const int b  = blk >> 8;
        const int n  = bx * 256 + t;
        const float* xb = x + (size_t)b * CIN * N + n;

        if (y < 8) {
            int cq = y;
            int d = n & 15, w = (n >> 4) & 15, h = n >> 8;
            int owl = (w > 0) ? -16 : 0,  owh = (w < 15) ? 16 : 0;
            int ohl = (h > 0) ? -256 : 0, ohh = (h < 15) ? 256 : 0;
            int odl = (d > 0) ? -1 : 0,   odh = (d < 15) ? 1 : 0;
            float mwl = (w > 0) ? 1.f : 0.f, mwh = (w < 15) ? 1.f : 0.f;
            float mhl = (h > 0) ? 1.f : 0.f, mhh = (h < 15) ? 1.f : 0.f;
            float mdl = (d > 0) ? 1.f : 0.f, mdh = (d < 15) ? 1.f : 0.f;
            float q = bq[cq], k = bk[cq], j = bj[cq];
            for (int c0 = 0; c0 < CIN; c0 += 8) {
                float xc[8], xwl[8], xwh[8], xhl[8], xhh[8], xdl[8], xdh[8];
#pragma unroll
                for (int u = 0; u < 8; ++u) {       // 56 independent loads in flight
                    const float* p = xb + (size_t)(c0 + u) * N;
                    xc[u]  = p[0];
                    xwl[u] = p[owl]; xwh[u] = p[owh];
                    xhl[u] = p[ohl]; xhh[u] = p[ohh];
                    xdl[u] = p[odl]; xdh[u] = p[odh];
                }
#pragma unroll
                for (int u = 0; u < 8; ++u) {
                    int c = c0 + u;
                    const float* wqr = wq + (cq * CIN + c) * 3;
                    const float* wkr = wk + (cq * CIN + c) * 3;
                    const float* wjr = wj + (cq * CIN + c) * 3;
                    q += wqr[0] * (xwl[u] * mwl) + wqr[1] * xc[u] + wqr[2] * (xwh[u] * mwh);
                    k += wkr[0] * (xhl[u] * mhl) + wkr[1] * xc[u] + wkr[2] * (xhh[u] * mhh);
                    j += wjr[0] * (xdl[u] * mdl) + wjr[1] * xc[u] + wjr[2] * (xdh[u] * mdh);
                }
            }
            size_t base = (size_t)(b * N + n) * 8 + cq;
            ws[OFF_QT + base] = q;
            ws[OFF_KT + base] = k;
            ws[OFF_JT + base] = j;
        } else {
            int yy = y - 8;
            int co0 = yy * 8;
            float acc[8];
#pragma unroll
            for (int i = 0; i < 8; ++i) acc[i] = bv[co0 + i];
            for (int c0 = 0; c0 < CIN; c0 += 8) {
                float xv[8];
#pragma unroll
                for (int u = 0; u < 8; ++u) xv[u] = xb[(size_t)(c0 + u) * N];
#pragma unroll
                for (int u = 0; u < 8; ++u)
#pragma unroll
                    for (int i = 0; i < 8; ++i)
                        acc[i] += wv[(co0 + i) * CIN + c0 + u] * xv[u];
                if ((c0 >> 3) == yy) {               // this block owns out-chunk yy
#pragma unroll
                    for (int u = 0; u < 8; ++u)
                        out[(size_t)(b * CIN + c0 + u) * N + n] = xv[u];
                }
            }
#pragma unroll
            for (int i = 0; i < 8; ++i)
                vbf[(size_t)(b * CIN + co0 + i) * N + n] = f2bf(acc[i]);
        }
    }

    grid_barrier(bar + 0);

    // ====== phase B: per-block kj recompute + qkj(16 rows) + softmax stats ==
    {
        const int lane = t & 63, wid = t >> 6;
        const int b    = blk >> 8;
        const float* ktb = ws + OFF_KT + (size_t)b * N * 8;
        const float* jtb = ws + OFF_JT + (size_t)b * N * 8;

        // --- kj = K J^T (8x8), recomputed redundantly per block ---
        float acc[64];
#pragma unroll
        for (int i = 0; i < 64; ++i) acc[i] = 0.f;
        for (int i = 0; i < 16; ++i) {
            int nn = i * 256 + t;
            const float4* kt = (const float4*)(ktb + (size_t)nn * 8);
            const float4* jt = (const float4*)(jtb + (size_t)nn * 8);
            float4 ka = kt[0], kb2 = kt[1], ja = jt[0], jb2 = jt[1];
            float kv[8] = {ka.x, ka.y, ka.z, ka.w, kb2.x, kb2.y, kb2.z, kb2.w};
            float jv[8] = {ja.x, ja.y, ja.z, ja.w, jb2.x, jb2.y, jb2.z, jb2.w};
#pragma unroll
            for (int c = 0; c < 8; ++c)
#pragma unroll
                for (int dd = 0; dd < 8; ++dd) acc[c * 8 + dd] += kv[c] * jv[dd];
        }
#pragma unroll
        for (int s = 32; s >= 1; s >>= 1)
#pragma unroll
            for (int i = 0; i < 64; ++i) acc[i] += __shfl_down(acc[i], s, 64);
        if (lane == 0) {
#pragma unroll
            for (int i = 0; i < 64; ++i) shm.b.kjpart[wid][i] = acc[i];
        }
        __syncthreads();
        if (t < 64)
            shm.b.kjs[t] = shm.b.kjpart[0][t] + shm.b.kjpart[1][t]
                         + shm.b.kjpart[2][t] + shm.b.kjpart[3][t];
        __syncthreads();

        // --- qkj for this wave's 4 rows (all lanes redundantly) ---
        float kjr[64];
#pragma unroll
        for (int i = 0; i < 64; ++i) kjr[i] = shm.b.kjs[i];
        const int r0 = blk * 16 + wid * 4;          // global row (b*N+n)
        float4 qa[4], qb[4];
#pragma unroll
        for (int rr = 0; rr < 4; ++rr) {
            const float4* q4 = (const float4*)(ws + OFF_QT + (size_t)(r0 + rr) * 8);
            float4 a4 = q4[0], b4 = q4[1];
            float qv[8] = {a4.x, a4.y, a4.z, a4.w, b4.x, b4.y, b4.z, b4.w};
            float o[8];
#pragma unroll
            for (int dd = 0; dd < 8; ++dd) {
                float a = 0.f;
#pragma unroll
                for (int c = 0; c < 8; ++c) a += qv[c] * kjr[c * 8 + dd];
                o[dd] = a;
            }
            qa[rr] = make_float4(o[0], o[1], o[2], o[3]);
            qb[rr] = make_float4(o[4], o[5], o[6], o[7]);
        }
        // write qkj rows to ws for phase C (lanes 0..31: (rr,dd) distributed)
        if (lane < 32) {
            const int rr = lane >> 3, dd = lane & 7;
            const float* qr = ws + OFF_QT + (size_t)(r0 + rr) * 8;
            float o = 0.f;
#pragma unroll
            for (int c = 0; c < 8; ++c) o += qr[c] * shm.b.kjs[c * 8 + dd];
            ws[OFF_QK + (size_t)r0 * 8 + lane] = o;   // == (r0+rr)*8 + dd
        }

        // --- softmax stats: online row softmax over all m, lanes split m ---
        float mx[4], sm2[4];
#pragma unroll
        for (int rr = 0; rr < 4; ++rr) { mx[rr] = -3.0e38f; sm2[rr] = 0.f; }
#pragma unroll 4
        for (int i = 0; i < 64; ++i) {
            const int m = i * 64 + lane;
            const float4* kk4 = (const float4*)(ktb + (size_t)m * 8);
            float4 ka = kk4[0], kb2 = kk4[1];
#pragma unroll
            for (int rr = 0; rr < 4; ++rr) {
                float a = qa[rr].x * ka.x + qa[rr].y * ka.y + qa[rr].z * ka.z + qa[rr].w * ka.w
                        + qb[rr].x * kb2.x + qb[rr].y * kb2.y + qb[rr].z * kb2.z + qb[rr].w * kb2.w;
                float nm = fmaxf(mx[rr], a);
                sm2[rr] = sm2[rr] * __expf(mx[rr] - nm) + __expf(a - nm);
                mx[rr] = nm;
            }
        }
#pragma unroll
        for (int s = 32; s >= 1; s >>= 1)
#pragma unroll
            for (int rr = 0; rr < 4; ++rr) {
                float omx = __shfl_xor(mx[rr], s, 64);
                float osm = __shfl_xor(sm2[rr], s, 64);
                float nm = fmaxf(mx[rr], omx);
                sm2[rr] = sm2[rr] * __expf(mx[rr] - nm) + osm * __expf(omx - nm);
                mx[rr] = nm;
            }
        if (lane == 0) {
            float g = gamma[0];
#pragma unroll
            for (int rr = 0; rr < 4; ++rr) {
                ws[OFF_MX + r0 + rr] = mx[rr];
                ws[OFF_SC + r0 + rr] = g / sm2[rr];   // gamma/rowsum folded
            }
        }
    }

    grid_barrier(bar + 1);

    // ========== phase C: out += V_bf16 . P'_bf16 via MFMA (old pass2) =======
    // 512 blocks = (64 m-tiles, 4 n-slices, 2 b); 16 chunks of 64 n per slice.
    {
        const int mt = blk & 63;
        const int ns = (blk >> 6) & 3;
        const int b  = blk >> 8;
        const int m0 = mt * 64;
        const float* qkT = ws + OFF_QK + (size_t)b * N * 8;
        const float* ktb = ws + OFF_KT + (size_t)b * N * 8;
        const float* mxv = ws + OFF_MX + (size_t)b * N;
        const float* scv = ws + OFF_SC + (size_t)b * N;
        const u16*   vb  = vbf + (size_t)b * CIN * N;

        if (t < 128) ((float4*)shm.c.ks)[t] = ((const float4*)(ktb + (size_t)m0 * 8))[t];

        const int lane = t & 63;
        const int wid  = t >> 6;        // wave id -> m-subtile
        const int l16  = lane & 15;
        const int lq   = lane >> 4;     // lane quad -> k-octet / acc row group
        const int vc   = t >> 3;        // V staging row 0..31
        const int vseg = t & 7;

        f32x4 acc[4];
#pragma unroll
        for (int i = 0; i < 4; ++i) acc[i] = (f32x4){0.f, 0.f, 0.f, 0.f};

        for (int ch = 0; ch < 16; ++ch) {
            const int n0 = ns * 1024 + ch * 64;
            const int n  = n0 + lane;
            const float4* q4 = (const float4*)(qkT + (size_t)n * 8);
            float4 qa = q4[0], qb = q4[1];
            float mxl = mxv[n], sl = scv[n];
            uint4 v0 = *(const uint4*)(vb + (size_t)vc        * N + n0 + vseg * 8);
            uint4 v1 = *(const uint4*)(vb + (size_t)(vc + 32) * N + n0 + vseg * 8);
            __syncthreads();            // prev chunk's MFMA reads done (chunk 0: ks staged)
#pragma unroll
            for (int r = 0; r < 16; ++r) {
                int mi = wid * 16 + r;
                float4 k0 = *(const float4*)&shm.c.ks[mi][0];
                float4 k1 = *(const float4*)&shm.c.ks[mi][4];
                float a = qa.x * k0.x + qa.y * k0.y + qa.z * k0.z + qa.w * k0.w
                        + qb.x * k1.x + qb.y * k1.y + qb.z * k1.z + qb.w * k1.w;
                shm.c.Pt[mi][lane] = f2bf(__expf(a - mxl) * sl);  // gamma/rowsum folded
            }
            *(uint4*)&shm.c.Vt[vc][vseg * 8]      = v0;
            *(uint4*)&shm.c.Vt[vc + 32][vseg * 8] = v1;
            __syncthreads();
#pragma unroll
            for (int kk = 0; kk < 2; ++kk) {
                int k0i = kk * 32 + lq * 8;
                bf16x8 bfrag = *(const bf16x8*)&shm.c.Pt[wid * 16 + l16][k0i];
#pragma unroll
                for (int ct = 0; ct < 4; ++ct) {
                    bf16x8 afrag = *(const bf16x8*)&shm.c.Vt[ct * 16 + l16][k0i];
                    acc[ct] = __builtin_amdgcn_mfma_f32_16x16x32_bf16(afrag, bfrag, acc[ct], 0, 0, 0);
                }
            }
        }
        float* ob = out + (size_t)b * CIN * N;
        const int mcol = m0 + wid * 16 + l16;
#pragma unroll
        for (int ct = 0; ct < 4; ++ct)
#pragma unroll
            for (int r = 0; r < 4; ++r) {
                int c = ct * 16 + lq * 4 + r;
                atomicAdd(&ob[(size_t)c * N + mcol], acc[ct][r]);
            }
    }
}

extern "C" void kernel_launch(void* const* d_in, const int* in_sizes, int n_in,
                              void* d_out, int out_size, void* d_ws, size_t ws_size,
                              hipStream_t stream) {
    const float* x  = (const float*)d_in[0];
    const float* wq = (const float*)d_in[1];
    const float* bq = (const float*)d_in[2];
    const float* wk = (const float*)d_in[3];
    const float* bk = (const float*)d_in[4];
    const float* wj = (const float*)d_in[5];
    const float* bj = (const float*)d_in[6];
    const float* wv = (const float*)d_in[7];
    const float* bv = (const float*)d_in[8];
    const float* gamma = (const float*)d_in[9];
    float* ws  = (float*)d_ws;
    float* out = (float*)d_out;
    u16* vbf = (u16*)(ws + OFF_V);

    // zero the two grid-barrier counters (ws is poisoned between iterations)
    hipMemsetAsync(ws + OFF_BAR, 0, 2 * sizeof(unsigned), stream);
    fused<<<dim3(512), dim3(256), 0, stream>>>(x, wq, bq, wk, bk, wj, bj, wv, bv,
                                               gamma, ws, vbf, out);
}

// Round 3
// 178.159 us; speedup vs baseline: 1.3666x; 1.3666x over previous
//
#include <hip/hip_runtime.h>

#define N 4096
#define CIN 64
#define NB 2

typedef unsigned short u16;
typedef short bf16x8 __attribute__((ext_vector_type(8)));
typedef float f32x4 __attribute__((ext_vector_type(4)));

// workspace layout (float offsets). OFF_V region holds bf16 (u16) V.
// OFF_QK holds qkj[n][8] = q[n] . kj
#define OFF_QT 0
#define OFF_KT (OFF_QT + NB*N*8)
#define OFF_JT (OFF_KT + NB*N*8)
#define OFF_V  (OFF_JT + NB*N*8)
#define OFF_QK (OFF_V + NB*CIN*N)
#define OFF_MX (OFF_QK + NB*N*8)
#define OFF_SC (OFF_MX + NB*N)

__device__ __forceinline__ u16 f2bf(float f) {
    union { float f; unsigned u; } v; v.f = f;
    unsigned r = (v.u + 0x7fffu + ((v.u >> 16) & 1u)) >> 16;  // RNE
    return (u16)r;
}

// ---- prep: 512-thread blocks, c-split across halves (16 waves/CU) ----------
// grid (16,16,2). t&255 = n-sub, t>>8 = c-half. LDS combine of partials.
__global__ __launch_bounds__(512, 4) void prep(
        const float* __restrict__ x,
        const float* __restrict__ wq, const float* __restrict__ bq,
        const float* __restrict__ wk, const float* __restrict__ bk,
        const float* __restrict__ wj, const float* __restrict__ bj,
        const float* __restrict__ wv, const float* __restrict__ bv,
        float* __restrict__ ws, u16* __restrict__ vbf, float* __restrict__ out) {
    __shared__ union {
        float qkj[3][256];
        float accv[256][8];
    } sh;
    const int t    = threadIdx.x;
    const int tn   = t & 255;
    const int half = t >> 8;               // c-half: 0 -> c 0..31, 1 -> c 32..63
    const int y    = blockIdx.y;
    const int b    = blockIdx.z;
    const int n    = blockIdx.x * 256 + tn;
    const float* xb = x + (size_t)b * CIN * N + n;
    const int c0base = half * 32;

    if (y < 8) {
        int cq = y;
        int d = n & 15, w = (n >> 4) & 15, h = n >> 8;
        int owl = (w > 0) ? -16 : 0,  owh = (w < 15) ? 16 : 0;
        int ohl = (h > 0) ? -256 : 0, ohh = (h < 15) ? 256 : 0;
        int odl = (d > 0) ? -1 : 0,   odh = (d < 15) ? 1 : 0;
        float mwl = (w > 0) ? 1.f : 0.f, mwh = (w < 15) ? 1.f : 0.f;
        float mhl = (h > 0) ? 1.f : 0.f, mhh = (h < 15) ? 1.f : 0.f;
        float mdl = (d > 0) ? 1.f : 0.f, mdh = (d < 15) ? 1.f : 0.f;
        float q = half ? 0.f : bq[cq];
        float k = half ? 0.f : bk[cq];
        float j = half ? 0.f : bj[cq];
        for (int c0i = 0; c0i < 32; c0i += 8) {
            const int c0 = c0base + c0i;
            float xc[8], xwl[8], xwh[8], xhl[8], xhh[8], xdl[8], xdh[8];
#pragma unroll
            for (int u = 0; u < 8; ++u) {       // 56 independent loads in flight
                const float* p = xb + (size_t)(c0 + u) * N;
                xc[u]  = p[0];
                xwl[u] = p[owl]; xwh[u] = p[owh];
                xhl[u] = p[ohl]; xhh[u] = p[ohh];
                xdl[u] = p[odl]; xdh[u] = p[odh];
            }
#pragma unroll
            for (int u = 0; u < 8; ++u) {
                int c = c0 + u;
                const float* wqr = wq + (cq * CIN + c) * 3;
                const float* wkr = wk + (cq * CIN + c) * 3;
                const float* wjr = wj + (cq * CIN + c) * 3;
                q += wqr[0] * (xwl[u] * mwl) + wqr[1] * xc[u] + wqr[2] * (xwh[u] * mwh);
                k += wkr[0] * (xhl[u] * mhl) + wkr[1] * xc[u] + wkr[2] * (xhh[u] * mhh);
                j += wjr[0] * (xdl[u] * mdl) + wjr[1] * xc[u] + wjr[2] * (xdh[u] * mdh);
            }
        }
        if (half) { sh.qkj[0][tn] = q; sh.qkj[1][tn] = k; sh.qkj[2][tn] = j; }
        __syncthreads();
        if (!half) {
            q += sh.qkj[0][tn]; k += sh.qkj[1][tn]; j += sh.qkj[2][tn];
            size_t base = (size_t)(b * N + n) * 8 + cq;
            ws[OFF_QT + base] = q;
            ws[OFF_KT + base] = k;
            ws[OFF_JT + base] = j;
        }
    } else {
        int yy = y - 8;
        int co0 = yy * 8;
        float acc[8];
#pragma unroll
        for (int i = 0; i < 8; ++i) acc[i] = half ? 0.f : bv[co0 + i];
        for (int c0i = 0; c0i < 32; c0i += 8) {
            const int c0 = c0base + c0i;
            float xv[8];
#pragma unroll
            for (int u = 0; u < 8; ++u) xv[u] = xb[(size_t)(c0 + u) * N];
#pragma unroll
            for (int u = 0; u < 8; ++u)
#pragma unroll
                for (int i = 0; i < 8; ++i)
                    acc[i] += wv[(co0 + i) * CIN + c0 + u] * xv[u];
            if ((c0 >> 3) == yy) {               // owning half copies out = x
#pragma unroll
                for (int u = 0; u < 8; ++u)
                    out[(size_t)(b * CIN + c0 + u) * N + n] = xv[u];
            }
        }
        if (half) {
#pragma unroll
            for (int i = 0; i < 8; ++i) sh.accv[tn][i] = acc[i];
        }
        __syncthreads();
        if (!half) {
#pragma unroll
            for (int i = 0; i < 8; ++i)
                vbf[(size_t)(b * CIN + co0 + i) * N + n] = f2bf(acc[i] + sh.accv[tn][i]);
        }
    }
}

// ---- statsB: kj recompute + qkj(16 rows) + softmax stats, m-split ----------
// grid 512, block 512 (8 waves, 16 waves/CU). Wave (wid&3) owns rows
// r0=blk*16+(wid&3)*4; wid>>2 selects m-half (32 iters each); LDS merge.
__global__ __launch_bounds__(512, 4) void statsB(float* __restrict__ ws,
                                                 const float* __restrict__ gamma) {
    __shared__ float kjpart[8][64];
    __shared__ float kjs[64];
    __shared__ float mxs[8][4], sms[8][4];
    const int t = threadIdx.x, lane = t & 63, wid = t >> 6;
    const int blk = blockIdx.x;
    const int b   = blk >> 8;
    const float* ktb = ws + OFF_KT + (size_t)b * N * 8;
    const float* jtb = ws + OFF_JT + (size_t)b * N * 8;

    // --- kj = K J^T (8x8), recomputed per block; 512 threads, 8 iters ---
    float acc[64];
#pragma unroll
    for (int i = 0; i < 64; ++i) acc[i] = 0.f;
    for (int i = 0; i < 8; ++i) {
        int nn = i * 512 + t;
        const float4* kt = (const float4*)(ktb + (size_t)nn * 8);
        const float4* jt = (const float4*)(jtb + (size_t)nn * 8);
        float4 ka = kt[0], kb2 = kt[1], ja = jt[0], jb2 = jt[1];
        float kv[8] = {ka.x, ka.y, ka.z, ka.w, kb2.x, kb2.y, kb2.z, kb2.w};
        float jv[8] = {ja.x, ja.y, ja.z, ja.w, jb2.x, jb2.y, jb2.z, jb2.w};
#pragma unroll
        for (int c = 0; c < 8; ++c)
#pragma unroll
            for (int dd = 0; dd < 8; ++dd) acc[c * 8 + dd] += kv[c] * jv[dd];
    }
#pragma unroll
    for (int s = 32; s >= 1; s >>= 1)
#pragma unroll
        for (int i = 0; i < 64; ++i) acc[i] += __shfl_down(acc[i], s, 64);
    if (lane == 0) {
#pragma unroll
        for (int i = 0; i < 64; ++i) kjpart[wid][i] = acc[i];
    }
    __syncthreads();
    if (t < 64)
        kjs[t] = kjpart[0][t] + kjpart[1][t] + kjpart[2][t] + kjpart[3][t]
               + kjpart[4][t] + kjpart[5][t] + kjpart[6][t] + kjpart[7][t];
    __syncthreads();

    // --- qkj for this wave's 4 rows (redundant across m-halves) ---
    float kjr[64];
#pragma unroll
    for (int i = 0; i < 64; ++i) kjr[i] = kjs[i];
    const int wrow  = wid & 3;
    const int mhalf = wid >> 2;
    const int r0 = blk * 16 + wrow * 4;          // global row (b*N+n)
    float4 qa[4], qb[4];
#pragma unroll
    for (int rr = 0; rr < 4; ++rr) {
        const float4* q4 = (const float4*)(ws + OFF_QT + (size_t)(r0 + rr) * 8);
        float4 a4 = q4[0], b4 = q4[1];
        float qv[8] = {a4.x, a4.y, a4.z, a4.w, b4.x, b4.y, b4.z, b4.w};
        float o[8];
#pragma unroll
        for (int dd = 0; dd < 8; ++dd) {
            float a = 0.f;
#pragma unroll
            for (int c = 0; c < 8; ++c) a += qv[c] * kjr[c * 8 + dd];
            o[dd] = a;
        }
        qa[rr] = make_float4(o[0], o[1], o[2], o[3]);
        qb[rr] = make_float4(o[4], o[5], o[6], o[7]);
    }
    // write qkj rows to ws for pass2 (m-half 0 waves only; lanes 0..31)
    if (mhalf == 0 && lane < 32) {
        const int rr = lane >> 3, dd = lane & 7;
        const float* qr = ws + OFF_QT + (size_t)(r0 + rr) * 8;
        float o = 0.f;
#pragma unroll
        for (int c = 0; c < 8; ++c) o += qr[c] * kjs[c * 8 + dd];
        ws[OFF_QK + (size_t)r0 * 8 + lane] = o;   // == (r0+rr)*8 + dd
    }

    // --- softmax stats: online over this wave's m-half (32 iters) ---
    float mx[4], sm2[4];
#pragma unroll
    for (int rr = 0; rr < 4; ++rr) { mx[rr] = -3.0e38f; sm2[rr] = 0.f; }
#pragma unroll 4
    for (int i = 0; i < 32; ++i) {
        const int m = mhalf * 2048 + i * 64 + lane;
        const float4* kk4 = (const float4*)(ktb + (size_t)m * 8);
        float4 ka = kk4[0], kb2 = kk4[1];
#pragma unroll
        for (int rr = 0; rr < 4; ++rr) {
            float a = qa[rr].x * ka.x + qa[rr].y * ka.y + qa[rr].z * ka.z + qa[rr].w * ka.w
                    + qb[rr].x * kb2.x + qb[rr].y * kb2.y + qb[rr].z * kb2.z + qb[rr].w * kb2.w;
            float nm = fmaxf(mx[rr], a);
            sm2[rr] = sm2[rr] * __expf(mx[rr] - nm) + __expf(a - nm);
            mx[rr] = nm;
        }
    }
#pragma unroll
    for (int s = 32; s >= 1; s >>= 1)
#pragma unroll
        for (int rr = 0; rr < 4; ++rr) {
            float omx = __shfl_xor(mx[rr], s, 64);
            float osm = __shfl_xor(sm2[rr], s, 64);
            float nm = fmaxf(mx[rr], omx);
            sm2[rr] = sm2[rr] * __expf(mx[rr] - nm) + osm * __expf(omx - nm);
            mx[rr] = nm;
        }
    if (lane == 0) {
#pragma unroll
        for (int rr = 0; rr < 4; ++rr) { mxs[wid][rr] = mx[rr]; sms[wid][rr] = sm2[rr]; }
    }
    __syncthreads();
    // merge the two m-halves and emit
    if (t < 16) {
        const int w = t >> 2, rr = t & 3;
        float m1 = mxs[w][rr], m2 = mxs[w + 4][rr];
        float s1 = sms[w][rr], s2 = sms[w + 4][rr];
        float nm = fmaxf(m1, m2);
        float sm = s1 * __expf(m1 - nm) + s2 * __expf(m2 - nm);
        ws[OFF_MX + blk * 16 + w * 4 + rr] = nm;
        ws[OFF_SC + blk * 16 + w * 4 + rr] = gamma[0] / sm;
    }
}

// ---- pass2: out += V_bf16 . (sc*exp(qkj[n].k[m]-mx))_bf16 via MFMA ----------
// grid (64, 8, 2) block 256 (verified round-0 kernel, unchanged).
__global__ __launch_bounds__(256) void pass2(const float* __restrict__ ws,
                                             const u16* __restrict__ vbf,
                                             float* __restrict__ out) {
    __shared__ u16 Pt[64][72];      // P' tile: [m][n]  (B-frag: B[k=n][col=m])
    __shared__ u16 Vt[64][72];      // V tile:  [c][n]  (A-frag: A[row=c][k=n])
    __shared__ float ks[64][8];     // k for this m-tile
    const int t  = threadIdx.x;
    const int b  = blockIdx.z;
    const int m0 = blockIdx.x * 64;
    const int ns = blockIdx.y;
    const float* qkT = ws + OFF_QK + (size_t)b * N * 8;
    const float* ktb = ws + OFF_KT + (size_t)b * N * 8;
    const float* mxv = ws + OFF_MX + (size_t)b * N;
    const float* scv = ws + OFF_SC + (size_t)b * N;
    const u16*   vb  = vbf + (size_t)b * CIN * N;

    if (t < 128) ((float4*)ks)[t] = ((const float4*)(ktb + (size_t)m0 * 8))[t];

    const int lane = t & 63;
    const int wid  = t >> 6;        // wave id -> m-subtile
    const int l16  = lane & 15;
    const int lq   = lane >> 4;     // lane quad -> k-octet / acc row group
    const int vc   = t >> 3;        // V staging row 0..31
    const int vseg = t & 7;

    f32x4 acc[4];
#pragma unroll
    for (int i = 0; i < 4; ++i) acc[i] = (f32x4){0.f, 0.f, 0.f, 0.f};

    for (int ch = 0; ch < 8; ++ch) {
        const int n0 = ns * 512 + ch * 64;
        const int n  = n0 + lane;
        const float4* q4 = (const float4*)(qkT + (size_t)n * 8);
        float4 qa = q4[0], qb = q4[1];
        float mxl = mxv[n], sl = scv[n];
        uint4 v0 = *(const uint4*)(vb + (size_t)vc        * N + n0 + vseg * 8);
        uint4 v1 = *(const uint4*)(vb + (size_t)(vc + 32) * N + n0 + vseg * 8);
        __syncthreads();            // prev chunk's MFMA reads done (chunk 0: ks staged)
#pragma unroll
        for (int r = 0; r < 16; ++r) {
            int mi = wid * 16 + r;
            float4 k0 = *(const float4*)&ks[mi][0];
            float4 k1 = *(const float4*)&ks[mi][4];
            float a = qa.x * k0.x + qa.y * k0.y + qa.z * k0.z + qa.w * k0.w
                    + qb.x * k1.x + qb.y * k1.y + qb.z * k1.z + qb.w * k1.w;
            Pt[mi][lane] = f2bf(__expf(a - mxl) * sl);  // gamma/rowsum folded in
        }
        *(uint4*)&Vt[vc][vseg * 8]      = v0;
        *(uint4*)&Vt[vc + 32][vseg * 8] = v1;
        __syncthreads();
#pragma unroll
        for (int kk = 0; kk < 2; ++kk) {
            int k0i = kk * 32 + lq * 8;
            bf16x8 bfrag = *(const bf16x8*)&Pt[wid * 16 + l16][k0i];
#pragma unroll
            for (int ct = 0; ct < 4; ++ct) {
                bf16x8 afrag = *(const bf16x8*)&Vt[ct * 16 + l16][k0i];
                acc[ct] = __builtin_amdgcn_mfma_f32_16x16x32_bf16(afrag, bfrag, acc[ct], 0, 0, 0);
            }
        }
    }
    float* ob = out + (size_t)b * CIN * N;
    const int mcol = m0 + wid * 16 + l16;
#pragma unroll
    for (int ct = 0; ct < 4; ++ct)
#pragma unroll
        for (int r = 0; r < 4; ++r) {
            int c = ct * 16 + lq * 4 + r;
            atomicAdd(&ob[(size_t)c * N + mcol], acc[ct][r]);
        }
}

extern "C" void kernel_launch(void* const* d_in, const int* in_sizes, int n_in,
                              void* d_out, int out_size, void* d_ws, size_t ws_size,
                              hipStream_t stream) {
    const float* x  = (const float*)d_in[0];
    const float* wq = (const float*)d_in[1];
    const float* bq = (const float*)d_in[2];
    const float* wk = (const float*)d_in[3];
    const float* bk = (const float*)d_in[4];
    const float* wj = (const float*)d_in[5];
    const float* bj = (const float*)d_in[6];
    const float* wv = (const float*)d_in[7];
    const float* bv = (const float*)d_in[8];
    const float* gamma = (const float*)d_in[9];
    float* ws  = (float*)d_ws;
    float* out = (float*)d_out;
    u16* vbf = (u16*)(ws + OFF_V);

    prep<<<dim3(16, 16, 2), 512, 0, stream>>>(x, wq, bq, wk, bk, wj, bj, wv, bv, ws, vbf, out);
    statsB<<<512, 512, 0, stream>>>(ws, gamma);
    pass2<<<dim3(64, 8, 2), 256, 0, stream>>>(ws, vbf, out);
}